// Round 5
// baseline (149.922 us; speedup 1.0000x reference)
//
#include <hip/hip_runtime.h>

#define BATCH 4
#define NPTS 16384
#define NQ 2048
#define NFEAT 64
#define NS 32
#define NCH 67        // 3 + NFEAT
#define GRID 10       // cell edge 0.1 == radius
#define NCELL 1000
#define CSTRIDE 1024  // per-batch stride for cellStart
#define MAXHIT 128    // hit-list capacity per query (expected ~68 hits)

__device__ __forceinline__ int prefix_popc(unsigned long long m) {
  return (int)__builtin_amdgcn_mbcnt_hi(
      (unsigned)(m >> 32), __builtin_amdgcn_mbcnt_lo((unsigned)m, 0u));
}

__device__ __forceinline__ void cell3(float x, float y, float z, int& cx,
                                      int& cy, int& cz) {
  cx = min(max((int)(x * 10.0f), 0), GRID - 1);
  cy = min(max((int)(y * 10.0f), 0), GRID - 1);
  cz = min(max((int)(z * 10.0f), 0), GRID - 1);
}

// ---------------------------------------------------------------------------
// prep: blocks 0..3 build the per-batch cell grid entirely in LDS
// (hist -> scan -> scatter); blocks 4.. transpose features (B,C,N)->(B,N,C).
// ---------------------------------------------------------------------------
__global__ __launch_bounds__(1024) void prep_kernel(
    const float* __restrict__ xyz, const float* __restrict__ feat,
    float* __restrict__ featT, float4* __restrict__ cellPts,
    int* __restrict__ cellStart) {
  __shared__ float4 smem[64 * 65 / 4];  // 16.6 KB shared by both roles
  int* lhist = (int*)smem;              // [1024]
  int* lscan = lhist + 1024;            // [1024]
  int* lfill = lscan + 1024;            // [1024]
  float(*tile)[65] = (float(*)[65])smem;
  const int tid = threadIdx.x;

  if (blockIdx.x < BATCH) {
    const int b = blockIdx.x;
    const float* xb = xyz + (size_t)b * NPTS * 3;
    lhist[tid] = 0;
    lfill[tid] = 0;
    __syncthreads();
#pragma unroll
    for (int c = 0; c < NPTS / 1024; c++) {
      const int i = c * 1024 + tid;
      const float x = xb[i * 3 + 0];
      const float y = xb[i * 3 + 1];
      const float z = xb[i * 3 + 2];
      int cx, cy, cz;
      cell3(x, y, z, cx, cy, cz);
      atomicAdd(&lhist[(cz * GRID + cy) * GRID + cx], 1);
    }
    __syncthreads();
    const int val = lhist[tid];
    lscan[tid] = val;
    __syncthreads();
    for (int d = 1; d < 1024; d <<= 1) {
      const int t2 = (tid >= d) ? lscan[tid - d] : 0;
      __syncthreads();
      lscan[tid] += t2;
      __syncthreads();
    }
    const int excl = lscan[tid] - val;
    if (tid <= NCELL) cellStart[b * CSTRIDE + tid] = excl;  // [NCELL]==NPTS
    lhist[tid] = excl;
    __syncthreads();
#pragma unroll
    for (int c = 0; c < NPTS / 1024; c++) {
      const int i = c * 1024 + tid;
      const float x = xb[i * 3 + 0];
      const float y = xb[i * 3 + 1];
      const float z = xb[i * 3 + 2];
      int cx, cy, cz;
      cell3(x, y, z, cx, cy, cz);
      const int cid = (cz * GRID + cy) * GRID + cx;
      const int pos = lhist[cid] + atomicAdd(&lfill[cid], 1);
      cellPts[(size_t)b * NPTS + pos] = make_float4(x, y, z, __int_as_float(i));
    }
  } else {
    const int t2 = blockIdx.x - BATCH;
    const int b = t2 >> 8;  // 256 tiles per batch
    const int n0 = (t2 & 255) * 64;
    const float* inb = feat + (size_t)b * NFEAT * NPTS;
    float* outb = featT + (size_t)b * NPTS * NFEAT;
    {
      const int c = tid >> 4;
      const int nq = (tid & 15) * 4;
      const float4 v = *(const float4*)&inb[(size_t)c * NPTS + n0 + nq];
      tile[c][nq + 0] = v.x;
      tile[c][nq + 1] = v.y;
      tile[c][nq + 2] = v.z;
      tile[c][nq + 3] = v.w;
    }
    __syncthreads();
    {
      const int n = tid >> 4;
      const int cq = (tid & 15) * 4;
      float4 v;
      v.x = tile[cq + 0][n];
      v.y = tile[cq + 1][n];
      v.z = tile[cq + 2][n];
      v.w = tile[cq + 3][n];
      *(float4*)&outb[(size_t)(n0 + n) * NFEAT + cq] = v;
    }
  }
}

// ---------------------------------------------------------------------------
// query: one wave per query, NO block barriers (all state per-wave; wave
// lockstep + compiler lgkmcnt order LDS). 8.5 KB LDS -> 32 waves/CU.
// Emits sel[query][k] = (dx, dy, dz, idx) coalesced.
// ---------------------------------------------------------------------------
__global__ __launch_bounds__(256) void query_kernel(
    const float* __restrict__ xyz, const float* __restrict__ new_xyz,
    const float4* __restrict__ cellPts, const int* __restrict__ cellStart,
    float4* __restrict__ sel) {
  __shared__ int H[4][MAXHIT];
  __shared__ float Hx[4][MAXHIT], Hy[4][MAXHIT], Hz[4][MAXHIT];
  __shared__ int S[4][NS];

  const int w = threadIdx.x >> 6;
  const int lane = threadIdx.x & 63;
  const int query = blockIdx.x * 4 + w;
  const int b = query >> 11;  // / NQ
  const int j = query & (NQ - 1);

  const float* q = new_xyz + ((size_t)b * NQ + j) * 3;
  const float qx = q[0], qy = q[1], qz = q[2];
  const float R2 = (float)(0.1 * 0.1);  // 0x3C23D70A — matches np exactly

  int cx, cy, cz;
  cell3(qx, qy, qz, cx, cy, cz);
  const int* cs = cellStart + b * CSTRIDE;
  const float4* cp = cellPts + (size_t)b * NPTS;

  H[w][lane] = 0x7fffffff;
  H[w][lane + 64] = 0x7fffffff;

  // preload all 9 segment bounds as scalar loads
  const int cxm = max(cx - 1, 0);
  const int cxp = min(cx + 1, GRID - 1);
  int sArr[9], eArr[9];
#pragma unroll
  for (int r = 0; r < 9; r++) {
    const int dy = r % 3 - 1, dz = r / 3 - 1;
    const int cyy = cy + dy, czz = cz + dz;
    const bool ok = ((unsigned)cyy < GRID) && ((unsigned)czz < GRID);
    const int rowbase = (czz * GRID + cyy) * GRID;
    const int i0 = __builtin_amdgcn_readfirstlane(ok ? rowbase + cxm : 0);
    const int i1 = __builtin_amdgcn_readfirstlane(ok ? rowbase + cxp + 1 : 0);
    const int sv = cs[i0];
    const int ev = cs[i1];
    sArr[r] = ok ? sv : 0;
    eArr[r] = ok ? ev : 0;
  }

  // collect all hits into per-wave LDS lists
  int count = 0;
#pragma unroll
  for (int r = 0; r < 9; r++) {
    const int s = sArr[r];
    const int e = eArr[r];
    for (int i = s + lane; i < e + 63; i += 64) {
      const float4 p = cp[min(i, NPTS - 1)];
      const float dxf = __fsub_rn(qx, p.x);
      const float dyf = __fsub_rn(qy, p.y);
      const float dzf = __fsub_rn(qz, p.z);
      const float d2 =
          __fadd_rn(__fadd_rn(__fmul_rn(dxf, dxf), __fmul_rn(dyf, dyf)),
                    __fmul_rn(dzf, dzf));
      const bool hit = (i < e) && (d2 < R2);
      const unsigned long long m = __ballot(hit);
      if (hit) {
        const int pos = count + prefix_popc(m);
        if (pos < MAXHIT) {
          H[w][pos] = (__float_as_int(p.w) << 7) | pos;  // key: idx|slot
          Hx[w][pos] = p.x;
          Hy[w][pos] = p.y;
          Hz[w][pos] = p.z;
        }
      }
      count += (int)__popcll(m);
    }
  }

  if (count <= MAXHIT) {
    // rank selection: smallest 32 of up to 128 unique keys, no sort
    const int k0 = H[w][lane];
    const int k1 = H[w][lane + 64];
    const int4* Hv = (const int4*)&H[w][0];
    int r0 = 0, r1 = 0, mn = 0x7fffffff;
#pragma unroll
    for (int t = 0; t < MAXHIT / 4; t++) {
      const int4 h = Hv[t];  // broadcast read, conflict-free, pipelined
      mn = min(mn, min(min(h.x, h.y), min(h.z, h.w)));
      r0 += (h.x < k0) + (h.y < k0) + (h.z < k0) + (h.w < k0);
      r1 += (h.x < k1) + (h.y < k1) + (h.z < k1) + (h.w < k1);
    }
    if (k0 != 0x7fffffff && r0 < NS) S[w][r0] = k0;
    if (k1 != 0x7fffffff && r1 < NS) S[w][r1] = k1;
    const int found = min(count, NS);
    if (lane >= found && lane < NS) S[w][lane] = (count > 0) ? mn : 0;
  } else {
    // overflow fallback (P ~ 1e-10): exact ordered sequential scan
    const float* xb = xyz + (size_t)b * NPTS * 3;
    int cnt2 = 0;
    for (int base = 0; base < NPTS; base += 64) {
      const int i = base + lane;
      const float px = xb[i * 3 + 0];
      const float py = xb[i * 3 + 1];
      const float pz = xb[i * 3 + 2];
      const float dxf = __fsub_rn(qx, px);
      const float dyf = __fsub_rn(qy, py);
      const float dzf = __fsub_rn(qz, pz);
      const float d2 =
          __fadd_rn(__fadd_rn(__fmul_rn(dxf, dxf), __fmul_rn(dyf, dyf)),
                    __fmul_rn(dzf, dzf));
      const bool hit = d2 < R2;
      const unsigned long long m = __ballot(hit);
      if (hit) {
        const int pos = cnt2 + prefix_popc(m);
        if (pos < NS) {
          S[w][pos] = (i << 7) | pos;
          Hx[w][pos] = px;
          Hy[w][pos] = py;
          Hz[w][pos] = pz;
        }
      }
      cnt2 += (int)__popcll(m);
      if (cnt2 >= NS) break;
    }
    const int found = min(cnt2, NS);
    if (lane < NS && lane >= found) S[w][lane] = found ? S[w][0] : 0;
  }
  if (count == 0 && lane == 0) {  // no hits -> point 0 per reference
    const float* xb = xyz + (size_t)b * NPTS * 3;
    Hx[w][0] = xb[0];
    Hy[w][0] = xb[1];
    Hz[w][0] = xb[2];
  }

  // emit selection, coalesced 512 B per query
  if (lane < NS) {
    const int packed = S[w][lane];
    const int pos = packed & (MAXHIT - 1);
    const int gi = packed >> 7;
    sel[(size_t)query * NS + lane] =
        make_float4(__fsub_rn(Hx[w][pos], qx), __fsub_rn(Hy[w][pos], qy),
                    __fsub_rn(Hz[w][pos], qz), __int_as_float(gi));
  }
}

// ---------------------------------------------------------------------------
// group: streaming gather -> LDS transpose -> coalesced float4 stores.
// One wave per query, no block barriers (per-wave LDS regions only).
// ---------------------------------------------------------------------------
__global__ __launch_bounds__(256) void group_kernel(
    const float4* __restrict__ sel, const float* __restrict__ featT,
    float* __restrict__ out) {
  __shared__ float F[4][35][33];  // pad 33: 2-way conflicts only (free)

  const int w = threadIdx.x >> 6;
  const int lane = threadIdx.x & 63;
  const int query = blockIdx.x * 4 + w;
  const int b = query >> 11;
  const int j = query & (NQ - 1);
  const int r8 = lane >> 3;  // row/channel selector
  const int l8 = lane & 7;   // float4 slot

  float4 s = make_float4(0.f, 0.f, 0.f, 0.f);
  if (lane < NS) s = sel[(size_t)query * NS + lane];
  const int giw = __float_as_int(s.w);

  if (lane < NS) {
    F[w][0][lane] = s.x;
    F[w][1][lane] = s.y;
    F[w][2][lane] = s.z;
  }

  const float* fb = featT + (size_t)b * NPTS * NFEAT;
  const size_t ob = ((size_t)b * NCH * NQ + j) * (size_t)NS;

  // pass 0: features 0..31 -> F rows 3..34; store channels 0..34
#pragma unroll
  for (int t = 0; t < 4; t++) {
    const int srow = t * 8 + r8;
    const int gi = __shfl(giw, srow);  // source lanes 0..31 hold sel
    const float4 v = *(const float4*)&fb[(size_t)gi * NFEAT + l8 * 4];
    F[w][3 + l8 * 4 + 0][srow] = v.x;
    F[w][3 + l8 * 4 + 1][srow] = v.y;
    F[w][3 + l8 * 4 + 2][srow] = v.z;
    F[w][3 + l8 * 4 + 3][srow] = v.w;
  }
#pragma unroll
  for (int c0 = 0; c0 < 35; c0 += 8) {
    const int c = c0 + r8;
    if (c < 35) {
      float4 v;
      v.x = F[w][c][l8 * 4 + 0];
      v.y = F[w][c][l8 * 4 + 1];
      v.z = F[w][c][l8 * 4 + 2];
      v.w = F[w][c][l8 * 4 + 3];
      *(float4*)&out[ob + (size_t)c * (NQ * NS) + l8 * 4] = v;
    }
  }

  // pass 1: features 32..63 -> F rows 0..31; store channels 35..66
  // (WAR vs pass-0 reads is safe: wave-lockstep + compiler lgkmcnt ordering)
#pragma unroll
  for (int t = 0; t < 4; t++) {
    const int srow = t * 8 + r8;
    const int gi = __shfl(giw, srow);
    const float4 v = *(const float4*)&fb[(size_t)gi * NFEAT + 32 + l8 * 4];
    F[w][l8 * 4 + 0][srow] = v.x;
    F[w][l8 * 4 + 1][srow] = v.y;
    F[w][l8 * 4 + 2][srow] = v.z;
    F[w][l8 * 4 + 3][srow] = v.w;
  }
#pragma unroll
  for (int c0 = 0; c0 < 32; c0 += 8) {
    const int r = c0 + r8;
    const int c = 35 + r;
    float4 v;
    v.x = F[w][r][l8 * 4 + 0];
    v.y = F[w][r][l8 * 4 + 1];
    v.z = F[w][r][l8 * 4 + 2];
    v.w = F[w][r][l8 * 4 + 3];
    *(float4*)&out[ob + (size_t)c * (NQ * NS) + l8 * 4] = v;
  }
}

// ---------------------------------------------------------------------------
// Fallback for tiny workspace: direct scan kernel (round-1, known-correct).
// ---------------------------------------------------------------------------
__global__ __launch_bounds__(256) void query_group_direct(
    const float* __restrict__ xyz, const float* __restrict__ new_xyz,
    const float* __restrict__ feat, float* __restrict__ out) {
  __shared__ int sidx[4][NS];
  const int w = threadIdx.x >> 6;
  const int lane = threadIdx.x & 63;
  const int query = blockIdx.x * 4 + w;
  const int b = query >> 11;
  const int j = query & (NQ - 1);
  const float* q = new_xyz + ((size_t)b * NQ + j) * 3;
  const float qx = q[0], qy = q[1], qz = q[2];
  const float* xb = xyz + (size_t)b * NPTS * 3;
  const float R2 = (float)(0.1 * 0.1);
  int count = 0;
  for (int base = 0; base < NPTS; base += 64) {
    const int i = base + lane;
    const float dx = __fsub_rn(qx, xb[i * 3 + 0]);
    const float dy = __fsub_rn(qy, xb[i * 3 + 1]);
    const float dz = __fsub_rn(qz, xb[i * 3 + 2]);
    const float d2 = __fadd_rn(
        __fadd_rn(__fmul_rn(dx, dx), __fmul_rn(dy, dy)), __fmul_rn(dz, dz));
    const bool hit = d2 < R2;
    const unsigned long long m = __ballot(hit);
    if (hit) {
      const int pos = count + prefix_popc(m);
      if (pos < NS) sidx[w][pos] = i;
    }
    count += (int)__popcll(m);
    if (count >= NS) break;
  }
  const int found = count < NS ? count : NS;
  const int fill = (found > 0) ? sidx[w][0] : 0;
  if (lane < NS && lane >= found) sidx[w][lane] = fill;
  const int k = lane & 31;
  const int half = lane >> 5;
  const int gi = sidx[w][k];
  const float px = xb[gi * 3 + 0], py = xb[gi * 3 + 1], pz = xb[gi * 3 + 2];
  const size_t obase = ((size_t)b * NCH * NQ + j) * (size_t)NS + k;
  for (int c = half; c < NCH; c += 2) {
    float v;
    if (c < 3) {
      v = (c == 0) ? __fsub_rn(px, qx)
                   : (c == 1) ? __fsub_rn(py, qy) : __fsub_rn(pz, qz);
    } else {
      v = feat[((size_t)b * NFEAT + (c - 3)) * NPTS + gi];
    }
    out[obase + (size_t)c * (NQ * NS)] = v;
  }
}

extern "C" void kernel_launch(void* const* d_in, const int* in_sizes, int n_in,
                              void* d_out, int out_size, void* d_ws,
                              size_t ws_size, hipStream_t stream) {
  const float* xyz     = (const float*)d_in[0];  // (B, N, 3)
  const float* new_xyz = (const float*)d_in[1];  // (B, NPOINT, 3)
  const float* feat    = (const float*)d_in[2];  // (B, C, N)
  float* out = (float*)d_out;                    // (B, 67, NPOINT, 32)

  const size_t szFeatT  = (size_t)BATCH * NPTS * NFEAT * sizeof(float);  // 16MB
  const size_t szCells  = (size_t)BATCH * NPTS * sizeof(float4);         // 1MB
  const size_t szCStart = (size_t)BATCH * CSTRIDE * sizeof(int);
  const size_t szSel    = (size_t)BATCH * NQ * NS * sizeof(float4);      // 4MB
  const size_t need = szFeatT + szCells + szCStart + szSel;

  const int nblocks = (BATCH * NQ) / 4;  // one wave per query

  if (ws_size >= need) {
    char* p = (char*)d_ws;
    float*  featT     = (float*)p;  p += szFeatT;
    float4* cellPts   = (float4*)p; p += szCells;
    int*    cellStart = (int*)p;    p += szCStart;
    float4* sel       = (float4*)p;

    prep_kernel<<<BATCH + BATCH * (NPTS / 64), 1024, 0, stream>>>(
        xyz, feat, featT, cellPts, cellStart);
    query_kernel<<<nblocks, 256, 0, stream>>>(xyz, new_xyz, cellPts, cellStart,
                                              sel);
    group_kernel<<<nblocks, 256, 0, stream>>>(sel, featT, out);
  } else {
    query_group_direct<<<nblocks, 256, 0, stream>>>(xyz, new_xyz, feat, out);
  }
}

// Round 7
// 138.449 us; speedup vs baseline: 1.0829x; 1.0829x over previous
//
#include <hip/hip_runtime.h>

#define BATCH 4
#define NPTS 16384
#define NQ 2048
#define NFEAT 64
#define NS 32
#define NCH 67        // 3 + NFEAT
#define GRID 10       // cell edge 0.1 == radius
#define NCELL 1000
#define CSTRIDE 1024  // per-batch stride for cellStart
#define MAXHIT 128    // hit-list capacity per query (expected ~68 hits)

__device__ __forceinline__ int prefix_popc(unsigned long long m) {
  return (int)__builtin_amdgcn_mbcnt_hi(
      (unsigned)(m >> 32), __builtin_amdgcn_mbcnt_lo((unsigned)m, 0u));
}

__device__ __forceinline__ void cell3(float x, float y, float z, int& cx,
                                      int& cy, int& cz) {
  cx = min(max((int)(x * 10.0f), 0), GRID - 1);
  cy = min(max((int)(y * 10.0f), 0), GRID - 1);
  cz = min(max((int)(z * 10.0f), 0), GRID - 1);
}

// ---------------------------------------------------------------------------
// prep (R5-validated verbatim): blocks 0..3 build the per-batch cell grid in
// LDS (hist -> scan -> scatter); blocks 4.. transpose (B,C,N)->(B,N,C).
// ---------------------------------------------------------------------------
__global__ __launch_bounds__(1024) void prep_kernel(
    const float* __restrict__ xyz, const float* __restrict__ feat,
    float* __restrict__ featT, float4* __restrict__ cellPts,
    int* __restrict__ cellStart) {
  __shared__ float4 smem[64 * 65 / 4];  // 16.6 KB shared by both roles
  int* lhist = (int*)smem;              // [1024]
  int* lscan = lhist + 1024;            // [1024]
  int* lfill = lscan + 1024;            // [1024]
  float(*tile)[65] = (float(*)[65])smem;
  const int tid = threadIdx.x;

  if (blockIdx.x < BATCH) {
    const int b = blockIdx.x;
    const float* xb = xyz + (size_t)b * NPTS * 3;
    lhist[tid] = 0;
    lfill[tid] = 0;
    __syncthreads();
#pragma unroll
    for (int c = 0; c < NPTS / 1024; c++) {
      const int i = c * 1024 + tid;
      const float x = xb[i * 3 + 0];
      const float y = xb[i * 3 + 1];
      const float z = xb[i * 3 + 2];
      int cx, cy, cz;
      cell3(x, y, z, cx, cy, cz);
      atomicAdd(&lhist[(cz * GRID + cy) * GRID + cx], 1);
    }
    __syncthreads();
    const int val = lhist[tid];
    lscan[tid] = val;
    __syncthreads();
    for (int d = 1; d < 1024; d <<= 1) {
      const int t2 = (tid >= d) ? lscan[tid - d] : 0;
      __syncthreads();
      lscan[tid] += t2;
      __syncthreads();
    }
    const int excl = lscan[tid] - val;
    if (tid <= NCELL) cellStart[b * CSTRIDE + tid] = excl;  // [NCELL]==NPTS
    lhist[tid] = excl;
    __syncthreads();
#pragma unroll
    for (int c = 0; c < NPTS / 1024; c++) {
      const int i = c * 1024 + tid;
      const float x = xb[i * 3 + 0];
      const float y = xb[i * 3 + 1];
      const float z = xb[i * 3 + 2];
      int cx, cy, cz;
      cell3(x, y, z, cx, cy, cz);
      const int cid = (cz * GRID + cy) * GRID + cx;
      const int pos = lhist[cid] + atomicAdd(&lfill[cid], 1);
      cellPts[(size_t)b * NPTS + pos] = make_float4(x, y, z, __int_as_float(i));
    }
  } else {
    const int t2 = blockIdx.x - BATCH;
    const int b = t2 >> 8;  // 256 tiles per batch
    const int n0 = (t2 & 255) * 64;
    const float* inb = feat + (size_t)b * NFEAT * NPTS;
    float* outb = featT + (size_t)b * NPTS * NFEAT;
    {
      const int c = tid >> 4;
      const int nq = (tid & 15) * 4;
      const float4 v = *(const float4*)&inb[(size_t)c * NPTS + n0 + nq];
      tile[c][nq + 0] = v.x;
      tile[c][nq + 1] = v.y;
      tile[c][nq + 2] = v.z;
      tile[c][nq + 3] = v.w;
    }
    __syncthreads();
    {
      const int n = tid >> 4;
      const int cq = (tid & 15) * 4;
      float4 v;
      v.x = tile[cq + 0][n];
      v.y = tile[cq + 1][n];
      v.z = tile[cq + 2][n];
      v.w = tile[cq + 3][n];
      *(float4*)&outb[(size_t)(n0 + n) * NFEAT + cq] = v;
    }
  }
}

// ---------------------------------------------------------------------------
// main: R3 structure (full barrier set) with raw idx keys, guarded sort
// loads, plain bounds preload, and global xyz re-read in the epilogue
// (Hx/Hy/Hz dropped: LDS 27 -> 21 KB, 5 -> 7 blocks/CU).
// ---------------------------------------------------------------------------
__global__ __launch_bounds__(256) void qg_main(
    const float* __restrict__ xyz, const float* __restrict__ new_xyz,
    const float* __restrict__ featT, const float4* __restrict__ cellPts,
    const int* __restrict__ cellStart, float* __restrict__ out) {
  __shared__ int H[4][MAXHIT];    // 2 KB
  __shared__ int S[4][NS];        // 0.5 KB
  __shared__ float F[4][35][33];  // 18.5 KB; pad 33: 2-way conflicts (free)

  const int w = threadIdx.x >> 6;
  const int lane = threadIdx.x & 63;
  const int query = blockIdx.x * 4 + w;
  const int b = query >> 11;  // / NQ
  const int j = query & (NQ - 1);

  const float* q = new_xyz + ((size_t)b * NQ + j) * 3;
  const float qx = q[0], qy = q[1], qz = q[2];
  const float R2 = (float)(0.1 * 0.1);  // 0x3C23D70A — matches np exactly

  int cx, cy, cz;
  cell3(qx, qy, qz, cx, cy, cz);
  const int* cs = cellStart + b * CSTRIDE;
  const float4* cp = cellPts + (size_t)b * NPTS;

  // ---- preload all 9 row bounds: unconditional clamped loads ----
  const int cxm = max(cx - 1, 0);
  const int cxp = min(cx + 1, GRID - 1);
  int sA[9], eA[9];
#pragma unroll
  for (int r = 0; r < 9; r++) {
    const int dy = r % 3 - 1, dz = r / 3 - 1;
    const int cyy = cy + dy, czz = cz + dz;
    const bool ok = ((unsigned)cyy < GRID) && ((unsigned)czz < GRID);
    const int rowbase = (czz * GRID + cyy) * GRID;
    const int i0 = ok ? rowbase + cxm : 0;
    const int i1 = ok ? rowbase + cxp + 1 : 0;
    const int sv = cs[i0];
    const int ev = cs[i1];
    sA[r] = ok ? sv : 0;
    eA[r] = ok ? ev : 0;
  }

  // ---- collect all hit indices into the per-wave LDS list ----
  int count = 0;
#pragma unroll
  for (int r = 0; r < 9; r++) {
    const int s = sA[r];
    const int e = eA[r];
    for (int i = s + lane; i < e + 63; i += 64) {
      const float4 p = cp[min(i, NPTS - 1)];
      const float dxf = __fsub_rn(qx, p.x);
      const float dyf = __fsub_rn(qy, p.y);
      const float dzf = __fsub_rn(qz, p.z);
      const float d2 =
          __fadd_rn(__fadd_rn(__fmul_rn(dxf, dxf), __fmul_rn(dyf, dyf)),
                    __fmul_rn(dzf, dzf));
      const bool hit = (i < e) && (d2 < R2);
      const unsigned long long m = __ballot(hit);
      if (hit) {
        const int pos = count + prefix_popc(m);
        if (pos < MAXHIT) H[w][pos] = __float_as_int(p.w);  // key = point idx
      }
      count += (int)__popcll(m);
    }
  }
  __syncthreads();  // A

  if (count <= MAXHIT) {
    // ---- register bitonic sort of 128 keys (guarded loads, no pre-init) ----
    int v0 = (lane < count) ? H[w][lane] : 0x7fffffff;
    int v1 = (lane + 64 < count) ? H[w][lane + 64] : 0x7fffffff;
#pragma unroll
    for (int k = 2; k <= 128; k <<= 1) {
#pragma unroll
      for (int jj = k >> 1; jj > 0; jj >>= 1) {
        if (jj == 64) {  // only when k==128: cross-register, same lane
          const int lo = min(v0, v1), hi = max(v0, v1);
          v0 = lo;
          v1 = hi;
        } else {
          const int o0 = __shfl_xor(v0, jj);
          const int o1 = __shfl_xor(v1, jj);
          const bool lower = (lane & jj) == 0;
          const bool up0 = (lane & k) == 0;         // element id = lane
          const bool up1 = ((lane + 64) & k) == 0;  // element id = lane+64
          v0 = (up0 == lower) ? min(v0, o0) : max(v0, o0);
          v1 = (up1 == lower) ? min(v1, o1) : max(v1, o1);
        }
      }
    }
    const int found = min(count, NS);
    const int fill0 = __shfl(v0, 0);  // smallest key = first hit idx
    if (lane < NS) S[w][lane] = (lane < found) ? v0 : (found ? fill0 : 0);
  } else {
    // ---- overflow fallback (P ~ 1e-10): exact ordered sequential scan ----
    const float* xb = xyz + (size_t)b * NPTS * 3;
    int cnt2 = 0;
    for (int base = 0; base < NPTS; base += 64) {
      const int i = base + lane;
      const float dxf = __fsub_rn(qx, xb[i * 3 + 0]);
      const float dyf = __fsub_rn(qy, xb[i * 3 + 1]);
      const float dzf = __fsub_rn(qz, xb[i * 3 + 2]);
      const float d2 =
          __fadd_rn(__fadd_rn(__fmul_rn(dxf, dxf), __fmul_rn(dyf, dyf)),
                    __fmul_rn(dzf, dzf));
      const bool hit = d2 < R2;
      const unsigned long long m = __ballot(hit);
      if (hit) {
        const int pos = cnt2 + prefix_popc(m);
        if (pos < NS) S[w][pos] = i;
      }
      cnt2 += (int)__popcll(m);
      if (cnt2 >= NS) break;
    }
    const int found = min(cnt2, NS);
    if (lane < NS && lane >= found) S[w][lane] = found ? S[w][0] : 0;
  }
  __syncthreads();  // B

  // ---- group phase: gather -> LDS transpose -> coalesced float4 stores ----
  const int r8 = lane >> 3;  // row/channel selector
  const int l8 = lane & 7;   // float4 slot
  const float* fb = featT + (size_t)b * NPTS * NFEAT;
  const float* xb = xyz + (size_t)b * NPTS * 3;
  const size_t ob = ((size_t)b * NCH * NQ + j) * (size_t)NS;

  // channels 0..2: re-read the 32 selected coords (L2-hot, one-time).
  // count==0 => S holds 0 => xyz[0]-q, matching the reference's idx=0 pad.
  if (lane < NS) {
    const int gi = S[w][lane];
    F[w][0][lane] = __fsub_rn(xb[gi * 3 + 0], qx);
    F[w][1][lane] = __fsub_rn(xb[gi * 3 + 1], qy);
    F[w][2][lane] = __fsub_rn(xb[gi * 3 + 2], qz);
  }

  // pass 0: features 0..31 -> F rows 3..34; store channels 0..34
#pragma unroll
  for (int t = 0; t < 4; t++) {
    const int srow = t * 8 + r8;
    const int gi = S[w][srow];
    const float4 v = *(const float4*)&fb[(size_t)gi * NFEAT + l8 * 4];
    F[w][3 + l8 * 4 + 0][srow] = v.x;
    F[w][3 + l8 * 4 + 1][srow] = v.y;
    F[w][3 + l8 * 4 + 2][srow] = v.z;
    F[w][3 + l8 * 4 + 3][srow] = v.w;
  }
  __syncthreads();  // C
#pragma unroll
  for (int c0 = 0; c0 < 35; c0 += 8) {
    const int c = c0 + r8;
    if (c < 35) {
      float4 v;
      v.x = F[w][c][l8 * 4 + 0];
      v.y = F[w][c][l8 * 4 + 1];
      v.z = F[w][c][l8 * 4 + 2];
      v.w = F[w][c][l8 * 4 + 3];
      *(float4*)&out[ob + (size_t)c * (NQ * NS) + l8 * 4] = v;
    }
  }
  __syncthreads();  // D (WAR: pass-1 overwrites F)

  // pass 1: features 32..63 -> F rows 0..31; store channels 35..66
#pragma unroll
  for (int t = 0; t < 4; t++) {
    const int srow = t * 8 + r8;
    const int gi = S[w][srow];
    const float4 v = *(const float4*)&fb[(size_t)gi * NFEAT + 32 + l8 * 4];
    F[w][l8 * 4 + 0][srow] = v.x;
    F[w][l8 * 4 + 1][srow] = v.y;
    F[w][l8 * 4 + 2][srow] = v.z;
    F[w][l8 * 4 + 3][srow] = v.w;
  }
  __syncthreads();  // E
#pragma unroll
  for (int c0 = 0; c0 < 32; c0 += 8) {
    const int r = c0 + r8;
    const int c = 35 + r;
    float4 v;
    v.x = F[w][r][l8 * 4 + 0];
    v.y = F[w][r][l8 * 4 + 1];
    v.z = F[w][r][l8 * 4 + 2];
    v.w = F[w][r][l8 * 4 + 3];
    *(float4*)&out[ob + (size_t)c * (NQ * NS) + l8 * 4] = v;
  }
}

// ---------------------------------------------------------------------------
// Fallback for tiny workspace: direct scan kernel (round-1, known-correct).
// ---------------------------------------------------------------------------
__global__ __launch_bounds__(256) void query_group_direct(
    const float* __restrict__ xyz, const float* __restrict__ new_xyz,
    const float* __restrict__ feat, float* __restrict__ out) {
  __shared__ int sidx[4][NS];
  const int w = threadIdx.x >> 6;
  const int lane = threadIdx.x & 63;
  const int query = blockIdx.x * 4 + w;
  const int b = query >> 11;
  const int j = query & (NQ - 1);
  const float* q = new_xyz + ((size_t)b * NQ + j) * 3;
  const float qx = q[0], qy = q[1], qz = q[2];
  const float* xb = xyz + (size_t)b * NPTS * 3;
  const float R2 = (float)(0.1 * 0.1);
  int count = 0;
  for (int base = 0; base < NPTS; base += 64) {
    const int i = base + lane;
    const float dx = __fsub_rn(qx, xb[i * 3 + 0]);
    const float dy = __fsub_rn(qy, xb[i * 3 + 1]);
    const float dz = __fsub_rn(qz, xb[i * 3 + 2]);
    const float d2 = __fadd_rn(
        __fadd_rn(__fmul_rn(dx, dx), __fmul_rn(dy, dy)), __fmul_rn(dz, dz));
    const bool hit = d2 < R2;
    const unsigned long long m = __ballot(hit);
    if (hit) {
      const int pos = count + prefix_popc(m);
      if (pos < NS) sidx[w][pos] = i;
    }
    count += (int)__popcll(m);
    if (count >= NS) break;
  }
  const int found = count < NS ? count : NS;
  const int fill = (found > 0) ? sidx[w][0] : 0;
  if (lane < NS && lane >= found) sidx[w][lane] = fill;
  const int k = lane & 31;
  const int half = lane >> 5;
  const int gi = sidx[w][k];
  const float px = xb[gi * 3 + 0], py = xb[gi * 3 + 1], pz = xb[gi * 3 + 2];
  const size_t obase = ((size_t)b * NCH * NQ + j) * (size_t)NS + k;
  for (int c = half; c < NCH; c += 2) {
    float v;
    if (c < 3) {
      v = (c == 0) ? __fsub_rn(px, qx)
                   : (c == 1) ? __fsub_rn(py, qy) : __fsub_rn(pz, qz);
    } else {
      v = feat[((size_t)b * NFEAT + (c - 3)) * NPTS + gi];
    }
    out[obase + (size_t)c * (NQ * NS)] = v;
  }
}

extern "C" void kernel_launch(void* const* d_in, const int* in_sizes, int n_in,
                              void* d_out, int out_size, void* d_ws,
                              size_t ws_size, hipStream_t stream) {
  const float* xyz     = (const float*)d_in[0];  // (B, N, 3)
  const float* new_xyz = (const float*)d_in[1];  // (B, NPOINT, 3)
  const float* feat    = (const float*)d_in[2];  // (B, C, N)
  float* out = (float*)d_out;                    // (B, 67, NPOINT, 32)

  const size_t szFeatT  = (size_t)BATCH * NPTS * NFEAT * sizeof(float);  // 16MB
  const size_t szCells  = (size_t)BATCH * NPTS * sizeof(float4);         // 1MB
  const size_t szCStart = (size_t)BATCH * CSTRIDE * sizeof(int);
  const size_t need = szFeatT + szCells + szCStart;

  const int nblocks = (BATCH * NQ) / 4;  // one wave per query

  if (ws_size >= need) {
    char* p = (char*)d_ws;
    float*  featT     = (float*)p;  p += szFeatT;
    float4* cellPts   = (float4*)p; p += szCells;
    int*    cellStart = (int*)p;

    prep_kernel<<<BATCH + BATCH * (NPTS / 64), 1024, 0, stream>>>(
        xyz, feat, featT, cellPts, cellStart);
    qg_main<<<nblocks, 256, 0, stream>>>(xyz, new_xyz, featT, cellPts,
                                         cellStart, out);
  } else {
    query_group_direct<<<nblocks, 256, 0, stream>>>(xyz, new_xyz, feat, out);
  }
}

// Round 8
// 127.981 us; speedup vs baseline: 1.1714x; 1.0818x over previous
//
#include <hip/hip_runtime.h>

#define BATCH 4
#define NPTS 16384
#define NQ 2048
#define NFEAT 64
#define NS 32
#define NCH 67        // 3 + NFEAT
#define GRID 10       // cell edge 0.1 == radius
#define NCELL 1000
#define CSTRIDE 1024  // per-batch stride for cellStart
#define MAXHIT 128    // hit-list capacity per query (expected ~68 hits)

__device__ __forceinline__ int prefix_popc(unsigned long long m) {
  return (int)__builtin_amdgcn_mbcnt_hi(
      (unsigned)(m >> 32), __builtin_amdgcn_mbcnt_lo((unsigned)m, 0u));
}

__device__ __forceinline__ void cell3(float x, float y, float z, int& cx,
                                      int& cy, int& cz) {
  cx = min(max((int)(x * 10.0f), 0), GRID - 1);
  cy = min(max((int)(y * 10.0f), 0), GRID - 1);
  cz = min(max((int)(z * 10.0f), 0), GRID - 1);
}

// ---------------------------------------------------------------------------
// prep (R5/R7-validated verbatim): blocks 0..3 build the per-batch cell grid
// in LDS (hist -> scan -> scatter); blocks 4.. transpose (B,C,N)->(B,N,C).
// ---------------------------------------------------------------------------
__global__ __launch_bounds__(1024) void prep_kernel(
    const float* __restrict__ xyz, const float* __restrict__ feat,
    float* __restrict__ featT, float4* __restrict__ cellPts,
    int* __restrict__ cellStart) {
  __shared__ float4 smem[64 * 65 / 4];  // 16.6 KB shared by both roles
  int* lhist = (int*)smem;              // [1024]
  int* lscan = lhist + 1024;            // [1024]
  int* lfill = lscan + 1024;            // [1024]
  float(*tile)[65] = (float(*)[65])smem;
  const int tid = threadIdx.x;

  if (blockIdx.x < BATCH) {
    const int b = blockIdx.x;
    const float* xb = xyz + (size_t)b * NPTS * 3;
    lhist[tid] = 0;
    lfill[tid] = 0;
    __syncthreads();
#pragma unroll
    for (int c = 0; c < NPTS / 1024; c++) {
      const int i = c * 1024 + tid;
      const float x = xb[i * 3 + 0];
      const float y = xb[i * 3 + 1];
      const float z = xb[i * 3 + 2];
      int cx, cy, cz;
      cell3(x, y, z, cx, cy, cz);
      atomicAdd(&lhist[(cz * GRID + cy) * GRID + cx], 1);
    }
    __syncthreads();
    const int val = lhist[tid];
    lscan[tid] = val;
    __syncthreads();
    for (int d = 1; d < 1024; d <<= 1) {
      const int t2 = (tid >= d) ? lscan[tid - d] : 0;
      __syncthreads();
      lscan[tid] += t2;
      __syncthreads();
    }
    const int excl = lscan[tid] - val;
    if (tid <= NCELL) cellStart[b * CSTRIDE + tid] = excl;  // [NCELL]==NPTS
    lhist[tid] = excl;
    __syncthreads();
#pragma unroll
    for (int c = 0; c < NPTS / 1024; c++) {
      const int i = c * 1024 + tid;
      const float x = xb[i * 3 + 0];
      const float y = xb[i * 3 + 1];
      const float z = xb[i * 3 + 2];
      int cx, cy, cz;
      cell3(x, y, z, cx, cy, cz);
      const int cid = (cz * GRID + cy) * GRID + cx;
      const int pos = lhist[cid] + atomicAdd(&lfill[cid], 1);
      cellPts[(size_t)b * NPTS + pos] = make_float4(x, y, z, __int_as_float(i));
    }
  } else {
    const int t2 = blockIdx.x - BATCH;
    const int b = t2 >> 8;  // 256 tiles per batch
    const int n0 = (t2 & 255) * 64;
    const float* inb = feat + (size_t)b * NFEAT * NPTS;
    float* outb = featT + (size_t)b * NPTS * NFEAT;
    {
      const int c = tid >> 4;
      const int nq = (tid & 15) * 4;
      const float4 v = *(const float4*)&inb[(size_t)c * NPTS + n0 + nq];
      tile[c][nq + 0] = v.x;
      tile[c][nq + 1] = v.y;
      tile[c][nq + 2] = v.z;
      tile[c][nq + 3] = v.w;
    }
    __syncthreads();
    {
      const int n = tid >> 4;
      const int cq = (tid & 15) * 4;
      float4 v;
      v.x = tile[cq + 0][n];
      v.y = tile[cq + 1][n];
      v.z = tile[cq + 2][n];
      v.w = tile[cq + 3][n];
      *(float4*)&outb[(size_t)(n0 + n) * NFEAT + cq] = v;
    }
  }
}

// ---------------------------------------------------------------------------
// main: R7 structure (validated) + ONE change: the first 64-lane chunk of
// all 9 cell rows is prefetched up front (9 independent loads, one waitcnt)
// instead of a serial load->count->load chain across rows.
// ---------------------------------------------------------------------------
__global__ __launch_bounds__(256) void qg_main(
    const float* __restrict__ xyz, const float* __restrict__ new_xyz,
    const float* __restrict__ featT, const float4* __restrict__ cellPts,
    const int* __restrict__ cellStart, float* __restrict__ out) {
  __shared__ int H[4][MAXHIT];    // 2 KB
  __shared__ int S[4][NS];        // 0.5 KB
  __shared__ float F[4][35][33];  // 18.5 KB; pad 33: 2-way conflicts (free)

  const int w = threadIdx.x >> 6;
  const int lane = threadIdx.x & 63;
  const int query = blockIdx.x * 4 + w;
  const int b = query >> 11;  // / NQ
  const int j = query & (NQ - 1);

  const float* q = new_xyz + ((size_t)b * NQ + j) * 3;
  const float qx = q[0], qy = q[1], qz = q[2];
  const float R2 = (float)(0.1 * 0.1);  // 0x3C23D70A — matches np exactly

  int cx, cy, cz;
  cell3(qx, qy, qz, cx, cy, cz);
  const int* cs = cellStart + b * CSTRIDE;
  const float4* cp = cellPts + (size_t)b * NPTS;

  // ---- preload all 9 row bounds: unconditional clamped loads ----
  const int cxm = max(cx - 1, 0);
  const int cxp = min(cx + 1, GRID - 1);
  int sA[9], eA[9];
#pragma unroll
  for (int r = 0; r < 9; r++) {
    const int dy = r % 3 - 1, dz = r / 3 - 1;
    const int cyy = cy + dy, czz = cz + dz;
    const bool ok = ((unsigned)cyy < GRID) && ((unsigned)czz < GRID);
    const int rowbase = (czz * GRID + cyy) * GRID;
    const int i0 = ok ? rowbase + cxm : 0;
    const int i1 = ok ? rowbase + cxp + 1 : 0;
    const int sv = cs[i0];
    const int ev = cs[i1];
    sA[r] = ok ? sv : 0;
    eA[r] = ok ? ev : 0;
  }

  // ---- prefetch first chunk of every row (rows are ~49 pts, so the inner
  // loop almost always runs exactly once; tail loop handles the rest) ----
  float4 P[9];
#pragma unroll
  for (int r = 0; r < 9; r++) P[r] = cp[min(sA[r] + lane, NPTS - 1)];

  // ---- collect all hit indices into the per-wave LDS list ----
  int count = 0;
#pragma unroll
  for (int r = 0; r < 9; r++) {
    const int e = eA[r];
    int i = sA[r] + lane;
    float4 p = P[r];
    while (true) {
      const float dxf = __fsub_rn(qx, p.x);
      const float dyf = __fsub_rn(qy, p.y);
      const float dzf = __fsub_rn(qz, p.z);
      const float d2 =
          __fadd_rn(__fadd_rn(__fmul_rn(dxf, dxf), __fmul_rn(dyf, dyf)),
                    __fmul_rn(dzf, dzf));
      const bool hit = (i < e) && (d2 < R2);
      const unsigned long long m = __ballot(hit);
      if (hit) {
        const int pos = count + prefix_popc(m);
        if (pos < MAXHIT) H[w][pos] = __float_as_int(p.w);  // key = point idx
      }
      count += (int)__popcll(m);
      i += 64;
      if (__ballot(i < e) == 0ull) break;  // uniform: common case exits here
      p = cp[min(i, NPTS - 1)];
    }
  }
  __syncthreads();  // A

  if (count <= MAXHIT) {
    // ---- register bitonic sort of 128 keys (guarded loads, no pre-init) ----
    int v0 = (lane < count) ? H[w][lane] : 0x7fffffff;
    int v1 = (lane + 64 < count) ? H[w][lane + 64] : 0x7fffffff;
#pragma unroll
    for (int k = 2; k <= 128; k <<= 1) {
#pragma unroll
      for (int jj = k >> 1; jj > 0; jj >>= 1) {
        if (jj == 64) {  // only when k==128: cross-register, same lane
          const int lo = min(v0, v1), hi = max(v0, v1);
          v0 = lo;
          v1 = hi;
        } else {
          const int o0 = __shfl_xor(v0, jj);
          const int o1 = __shfl_xor(v1, jj);
          const bool lower = (lane & jj) == 0;
          const bool up0 = (lane & k) == 0;         // element id = lane
          const bool up1 = ((lane + 64) & k) == 0;  // element id = lane+64
          v0 = (up0 == lower) ? min(v0, o0) : max(v0, o0);
          v1 = (up1 == lower) ? min(v1, o1) : max(v1, o1);
        }
      }
    }
    const int found = min(count, NS);
    const int fill0 = __shfl(v0, 0);  // smallest key = first hit idx
    if (lane < NS) S[w][lane] = (lane < found) ? v0 : (found ? fill0 : 0);
  } else {
    // ---- overflow fallback (P ~ 1e-10): exact ordered sequential scan ----
    const float* xb = xyz + (size_t)b * NPTS * 3;
    int cnt2 = 0;
    for (int base = 0; base < NPTS; base += 64) {
      const int i = base + lane;
      const float dxf = __fsub_rn(qx, xb[i * 3 + 0]);
      const float dyf = __fsub_rn(qy, xb[i * 3 + 1]);
      const float dzf = __fsub_rn(qz, xb[i * 3 + 2]);
      const float d2 =
          __fadd_rn(__fadd_rn(__fmul_rn(dxf, dxf), __fmul_rn(dyf, dyf)),
                    __fmul_rn(dzf, dzf));
      const bool hit = d2 < R2;
      const unsigned long long m = __ballot(hit);
      if (hit) {
        const int pos = cnt2 + prefix_popc(m);
        if (pos < NS) S[w][pos] = i;
      }
      cnt2 += (int)__popcll(m);
      if (cnt2 >= NS) break;
    }
    const int found = min(cnt2, NS);
    if (lane < NS && lane >= found) S[w][lane] = found ? S[w][0] : 0;
  }
  __syncthreads();  // B

  // ---- group phase: gather -> LDS transpose -> coalesced float4 stores ----
  const int r8 = lane >> 3;  // row/channel selector
  const int l8 = lane & 7;   // float4 slot
  const float* fb = featT + (size_t)b * NPTS * NFEAT;
  const float* xb = xyz + (size_t)b * NPTS * 3;
  const size_t ob = ((size_t)b * NCH * NQ + j) * (size_t)NS;

  // channels 0..2: re-read the 32 selected coords (L2-hot, one-time).
  // count==0 => S holds 0 => xyz[0]-q, matching the reference's idx=0 pad.
  if (lane < NS) {
    const int gi = S[w][lane];
    F[w][0][lane] = __fsub_rn(xb[gi * 3 + 0], qx);
    F[w][1][lane] = __fsub_rn(xb[gi * 3 + 1], qy);
    F[w][2][lane] = __fsub_rn(xb[gi * 3 + 2], qz);
  }

  // pass 0: features 0..31 -> F rows 3..34; store channels 0..34
#pragma unroll
  for (int t = 0; t < 4; t++) {
    const int srow = t * 8 + r8;
    const int gi = S[w][srow];
    const float4 v = *(const float4*)&fb[(size_t)gi * NFEAT + l8 * 4];
    F[w][3 + l8 * 4 + 0][srow] = v.x;
    F[w][3 + l8 * 4 + 1][srow] = v.y;
    F[w][3 + l8 * 4 + 2][srow] = v.z;
    F[w][3 + l8 * 4 + 3][srow] = v.w;
  }
  __syncthreads();  // C
#pragma unroll
  for (int c0 = 0; c0 < 35; c0 += 8) {
    const int c = c0 + r8;
    if (c < 35) {
      float4 v;
      v.x = F[w][c][l8 * 4 + 0];
      v.y = F[w][c][l8 * 4 + 1];
      v.z = F[w][c][l8 * 4 + 2];
      v.w = F[w][c][l8 * 4 + 3];
      *(float4*)&out[ob + (size_t)c * (NQ * NS) + l8 * 4] = v;
    }
  }
  __syncthreads();  // D (WAR: pass-1 overwrites F)

  // pass 1: features 32..63 -> F rows 0..31; store channels 35..66
#pragma unroll
  for (int t = 0; t < 4; t++) {
    const int srow = t * 8 + r8;
    const int gi = S[w][srow];
    const float4 v = *(const float4*)&fb[(size_t)gi * NFEAT + 32 + l8 * 4];
    F[w][l8 * 4 + 0][srow] = v.x;
    F[w][l8 * 4 + 1][srow] = v.y;
    F[w][l8 * 4 + 2][srow] = v.z;
    F[w][l8 * 4 + 3][srow] = v.w;
  }
  __syncthreads();  // E
#pragma unroll
  for (int c0 = 0; c0 < 32; c0 += 8) {
    const int r = c0 + r8;
    const int c = 35 + r;
    float4 v;
    v.x = F[w][r][l8 * 4 + 0];
    v.y = F[w][r][l8 * 4 + 1];
    v.z = F[w][r][l8 * 4 + 2];
    v.w = F[w][r][l8 * 4 + 3];
    *(float4*)&out[ob + (size_t)c * (NQ * NS) + l8 * 4] = v;
  }
}

// ---------------------------------------------------------------------------
// Fallback for tiny workspace: direct scan kernel (round-1, known-correct).
// ---------------------------------------------------------------------------
__global__ __launch_bounds__(256) void query_group_direct(
    const float* __restrict__ xyz, const float* __restrict__ new_xyz,
    const float* __restrict__ feat, float* __restrict__ out) {
  __shared__ int sidx[4][NS];
  const int w = threadIdx.x >> 6;
  const int lane = threadIdx.x & 63;
  const int query = blockIdx.x * 4 + w;
  const int b = query >> 11;
  const int j = query & (NQ - 1);
  const float* q = new_xyz + ((size_t)b * NQ + j) * 3;
  const float qx = q[0], qy = q[1], qz = q[2];
  const float* xb = xyz + (size_t)b * NPTS * 3;
  const float R2 = (float)(0.1 * 0.1);
  int count = 0;
  for (int base = 0; base < NPTS; base += 64) {
    const int i = base + lane;
    const float dx = __fsub_rn(qx, xb[i * 3 + 0]);
    const float dy = __fsub_rn(qy, xb[i * 3 + 1]);
    const float dz = __fsub_rn(qz, xb[i * 3 + 2]);
    const float d2 = __fadd_rn(
        __fadd_rn(__fmul_rn(dx, dx), __fmul_rn(dy, dy)), __fmul_rn(dz, dz));
    const bool hit = d2 < R2;
    const unsigned long long m = __ballot(hit);
    if (hit) {
      const int pos = count + prefix_popc(m);
      if (pos < NS) sidx[w][pos] = i;
    }
    count += (int)__popcll(m);
    if (count >= NS) break;
  }
  const int found = count < NS ? count : NS;
  const int fill = (found > 0) ? sidx[w][0] : 0;
  if (lane < NS && lane >= found) sidx[w][lane] = fill;
  const int k = lane & 31;
  const int half = lane >> 5;
  const int gi = sidx[w][k];
  const float px = xb[gi * 3 + 0], py = xb[gi * 3 + 1], pz = xb[gi * 3 + 2];
  const size_t obase = ((size_t)b * NCH * NQ + j) * (size_t)NS + k;
  for (int c = half; c < NCH; c += 2) {
    float v;
    if (c < 3) {
      v = (c == 0) ? __fsub_rn(px, qx)
                   : (c == 1) ? __fsub_rn(py, qy) : __fsub_rn(pz, qz);
    } else {
      v = feat[((size_t)b * NFEAT + (c - 3)) * NPTS + gi];
    }
    out[obase + (size_t)c * (NQ * NS)] = v;
  }
}

extern "C" void kernel_launch(void* const* d_in, const int* in_sizes, int n_in,
                              void* d_out, int out_size, void* d_ws,
                              size_t ws_size, hipStream_t stream) {
  const float* xyz     = (const float*)d_in[0];  // (B, N, 3)
  const float* new_xyz = (const float*)d_in[1];  // (B, NPOINT, 3)
  const float* feat    = (const float*)d_in[2];  // (B, C, N)
  float* out = (float*)d_out;                    // (B, 67, NPOINT, 32)

  const size_t szFeatT  = (size_t)BATCH * NPTS * NFEAT * sizeof(float);  // 16MB
  const size_t szCells  = (size_t)BATCH * NPTS * sizeof(float4);         // 1MB
  const size_t szCStart = (size_t)BATCH * CSTRIDE * sizeof(int);
  const size_t need = szFeatT + szCells + szCStart;

  const int nblocks = (BATCH * NQ) / 4;  // one wave per query

  if (ws_size >= need) {
    char* p = (char*)d_ws;
    float*  featT     = (float*)p;  p += szFeatT;
    float4* cellPts   = (float4*)p; p += szCells;
    int*    cellStart = (int*)p;

    prep_kernel<<<BATCH + BATCH * (NPTS / 64), 1024, 0, stream>>>(
        xyz, feat, featT, cellPts, cellStart);
    qg_main<<<nblocks, 256, 0, stream>>>(xyz, new_xyz, featT, cellPts,
                                         cellStart, out);
  } else {
    query_group_direct<<<nblocks, 256, 0, stream>>>(xyz, new_xyz, feat, out);
  }
}